// Round 1
// baseline (416.595 us; speedup 1.0000x reference)
//
#include <hip/hip_runtime.h>

#define DIN 128
#define DOUT 32
#define SLOPE 0.2f

// ---------------- Kernel A: h = x@W^T + b ; s2 = leaky(h)@a2 ----------------
// 256 threads = 8 rows x 32 cols. W staged in LDS with +1 pad (bank-conflict free).
__global__ __launch_bounds__(256) void gat_linear(
    const float* __restrict__ x, const float* __restrict__ W,
    const float* __restrict__ b, const float* __restrict__ a2,
    float* __restrict__ h, float* __restrict__ s2, int N)
{
    __shared__ float Wl[DOUT * (DIN + 1)];
    __shared__ float xs[8 * DIN];
    int tid = threadIdx.x;
    for (int idx = tid; idx < DOUT * DIN; idx += 256) {
        int col = idx >> 7, k = idx & 127;
        Wl[col * (DIN + 1) + k] = W[idx];
    }
    // stage 8 rows of x (coalesced float4: 256 threads x 16B = 8*128 floats)
    long base4 = (long)blockIdx.x * (8 * DIN / 4) + tid;   // float4 index
    if (base4 * 4 < (long)N * DIN) {
        ((float4*)xs)[tid] = ((const float4*)x)[base4];
    }
    __syncthreads();

    int rl = tid >> 5, col = tid & 31;
    int r = blockIdx.x * 8 + rl;
    if (r >= N) return;

    const float* xr = &xs[rl * DIN];
    const float* wc = &Wl[col * (DIN + 1)];
    float acc = 0.f;
#pragma unroll 8
    for (int k = 0; k < DIN; ++k) acc += xr[k] * wc[k];

    float hv = acc + b[col];
    h[(long)r * DOUT + col] = hv;
    float z = hv > 0.f ? hv : SLOPE * hv;
    float p = z * a2[col];
#pragma unroll
    for (int off = 16; off; off >>= 1) p += __shfl_xor(p, off, 32);
    if (col == 0) s2[r] = p;
}

// ---------------- Kernel B: degree histogram over src ----------------
__global__ void gat_hist(const int* __restrict__ src, int E, int* __restrict__ deg)
{
    int e = blockIdx.x * 256 + threadIdx.x;
    if (e < E) atomicAdd(&deg[src[e]], 1);
}

// ---------------- Scan level 1: 1024-elem chunks, exclusive ----------------
__global__ __launch_bounds__(256) void gat_scan1(
    const int* __restrict__ deg, int* __restrict__ offs, int* __restrict__ sums, int N)
{
    __shared__ int sh[256];
    int tid = threadIdx.x;
    int base = blockIdx.x * 1024 + tid * 4;
    int v0 = base + 0 < N ? deg[base + 0] : 0;
    int v1 = base + 1 < N ? deg[base + 1] : 0;
    int v2 = base + 2 < N ? deg[base + 2] : 0;
    int v3 = base + 3 < N ? deg[base + 3] : 0;
    int tsum = v0 + v1 + v2 + v3;
    sh[tid] = tsum;
    __syncthreads();
    for (int off = 1; off < 256; off <<= 1) {
        int t = (tid >= off) ? sh[tid - off] : 0;
        __syncthreads();
        sh[tid] += t;
        __syncthreads();
    }
    int excl = sh[tid] - tsum;
    if (base + 0 < N) offs[base + 0] = excl;
    if (base + 1 < N) offs[base + 1] = excl + v0;
    if (base + 2 < N) offs[base + 2] = excl + v0 + v1;
    if (base + 3 < N) offs[base + 3] = excl + v0 + v1 + v2;
    if (tid == 0) sums[blockIdx.x] = sh[255];
}

// ---------------- Scan level 2: single block over chunk sums (<=128) --------
__global__ void gat_scan2(int* __restrict__ sums, int nsums)
{
    __shared__ int sh[128];
    int tid = threadIdx.x;
    int v = tid < nsums ? sums[tid] : 0;
    sh[tid] = v;
    __syncthreads();
    for (int off = 1; off < 128; off <<= 1) {
        int t = (tid >= off) ? sh[tid - off] : 0;
        __syncthreads();
        sh[tid] += t;
        __syncthreads();
    }
    if (tid < nsums) sums[tid] = sh[tid] - v;
}

// ---------------- Scan level 3: add chunk base, init cursor ----------------
__global__ void gat_scan3(int* __restrict__ offs, const int* __restrict__ sums,
                          int* __restrict__ cursor, int N, int E)
{
    int i = blockIdx.x * 256 + threadIdx.x;
    if (i < N) {
        int v = offs[i] + sums[i >> 10];
        offs[i] = v;
        cursor[i] = v;
    }
    if (i == 0) offs[N] = E;
}

// ---------------- Scatter edges into CSR ----------------
__global__ void gat_scatter(const int* __restrict__ src, const int* __restrict__ dst,
                            int E, int* __restrict__ cursor, int* __restrict__ ebuf)
{
    int e = blockIdx.x * 256 + threadIdx.x;
    if (e < E) {
        int s = src[e];
        int pos = atomicAdd(&cursor[s], 1);
        ebuf[pos] = dst[e];
    }
}

// ---------------- Aggregate: online segment-softmax + weighted sum ----------
// 32 lanes per node (lane = output col), 8 nodes per 256-thread block.
// Self-loop handled implicitly as the initial state.
__global__ __launch_bounds__(256) void gat_aggregate(
    const float* __restrict__ h, const float* __restrict__ s2,
    const int* __restrict__ offs, const int* __restrict__ ebuf,
    float* __restrict__ out, int N)
{
    int tid = threadIdx.x;
    int i = blockIdx.x * 8 + (tid >> 5);
    if (i >= N) return;
    int col = tid & 31;

    int start = offs[i], end = offs[i + 1];
    float m = s2[i];                      // self-loop score
    float d = 1.0f;                       // exp(0)
    float acc = h[(long)i * DOUT + col];  // self-loop contribution

    for (int e = start; e < end; ++e) {
        int dn = ebuf[e];                         // broadcast load
        float v = s2[dn];                         // broadcast load
        float hv = h[(long)dn * DOUT + col];      // coalesced 128B row
        float p;
        if (v > m) {
            float sc = __expf(m - v);
            d *= sc; acc *= sc; m = v;
            p = 1.0f;
        } else {
            p = __expf(v - m);
        }
        d += p;
        acc += p * hv;
    }
    out[(long)i * DOUT + col] = acc / d;
}

extern "C" void kernel_launch(void* const* d_in, const int* in_sizes, int n_in,
                              void* d_out, int out_size, void* d_ws, size_t ws_size,
                              hipStream_t stream)
{
    const float* x  = (const float*)d_in[0];
    const int*   ei = (const int*)d_in[1];
    const float* W  = (const float*)d_in[2];
    const float* b  = (const float*)d_in[3];
    // d_in[4] = a1_w: unused — s1 cancels inside the segment softmax.
    const float* a2 = (const float*)d_in[5];
    float* out = (float*)d_out;

    int N = in_sizes[0] / DIN;
    int E = in_sizes[1] / 2;
    const int* src = ei;
    const int* dst = ei + E;

    char* ws = (char*)d_ws;
    float* h      = (float*)ws;  ws += (size_t)N * DOUT * sizeof(float);
    float* s2     = (float*)ws;  ws += (size_t)N * sizeof(float);
    int*   deg    = (int*)ws;    ws += (size_t)N * sizeof(int);
    int*   offs   = (int*)ws;    ws += (size_t)(N + 1) * sizeof(int);
    int*   cursor = (int*)ws;    ws += (size_t)N * sizeof(int);
    int*   sums   = (int*)ws;    ws += 128 * sizeof(int);
    int*   ebuf   = (int*)ws;    ws += (size_t)E * sizeof(int);

    int nchunks = (N + 1023) / 1024;   // 98 for N=100000 (<=128 required)

    hipMemsetAsync(deg, 0, (size_t)N * sizeof(int), stream);
    gat_linear  <<<(N + 7) / 8,   256, 0, stream>>>(x, W, b, a2, h, s2, N);
    gat_hist    <<<(E + 255) / 256, 256, 0, stream>>>(src, E, deg);
    gat_scan1   <<<nchunks,       256, 0, stream>>>(deg, offs, sums, N);
    gat_scan2   <<<1,             128, 0, stream>>>(sums, nchunks);
    gat_scan3   <<<(N + 255) / 256, 256, 0, stream>>>(offs, sums, cursor, N, E);
    gat_scatter <<<(E + 255) / 256, 256, 0, stream>>>(src, dst, E, cursor, ebuf);
    gat_aggregate<<<(N + 7) / 8,  256, 0, stream>>>(h, s2, offs, ebuf, out, N);
}

// Round 2
// 306.468 us; speedup vs baseline: 1.3593x; 1.3593x over previous
//
#include <hip/hip_runtime.h>

#define DIN 128
#define DOUT 32
#define SLOPE 0.2f

// ---------------- Kernel A: h = x@W^T + b ; es2 = exp(leaky(h)@a2) ; g = es2*h
// 256 threads = 8 rows x 32 cols. W staged in LDS with +1 pad.
__global__ __launch_bounds__(256) void gat_linear(
    const float* __restrict__ x, const float* __restrict__ W,
    const float* __restrict__ b, const float* __restrict__ a2,
    float* __restrict__ g, float* __restrict__ es2, int N)
{
    __shared__ float Wl[DOUT * (DIN + 1)];
    __shared__ float xs[8 * DIN];
    int tid = threadIdx.x;
    for (int idx = tid; idx < DOUT * DIN; idx += 256) {
        int col = idx >> 7, k = idx & 127;
        Wl[col * (DIN + 1) + k] = W[idx];
    }
    // stage 8 rows of x (coalesced float4: 256 threads x 16B = 8*128 floats)
    long base4 = (long)blockIdx.x * (8 * DIN / 4) + tid;   // float4 index
    if (base4 * 4 < (long)N * DIN) {
        ((float4*)xs)[tid] = ((const float4*)x)[base4];
    }
    __syncthreads();

    int rl = tid >> 5, col = tid & 31;
    int r = blockIdx.x * 8 + rl;
    if (r >= N) return;

    const float* xr = &xs[rl * DIN];
    const float* wc = &Wl[col * (DIN + 1)];
    float acc = 0.f;
#pragma unroll 8
    for (int k = 0; k < DIN; ++k) acc += xr[k] * wc[k];

    float hv = acc + b[col];
    float z = hv > 0.f ? hv : SLOPE * hv;
    float p = z * a2[col];
#pragma unroll
    for (int off = 16; off; off >>= 1) p += __shfl_xor(p, off, 32);
    // all 32 lanes now hold s2[r]; softmax shift-invariance => no max needed
    float ev = __expf(p);
    g[(long)r * DOUT + col] = ev * hv;
    if (col == 0) es2[r] = ev;
}

// ---------------- Kernel B: build per-src linked lists (coalesced writes) ---
// rec[e] = {next_edge, dst}; head[s] = most recent edge of s.
__global__ __launch_bounds__(256) void gat_build(
    const int* __restrict__ src, const int* __restrict__ dst, int E,
    int* __restrict__ head, int2* __restrict__ rec)
{
    int e = blockIdx.x * 256 + threadIdx.x;
    if (e >= E) return;
    int s = src[e];
    int d = dst[e];
    int prev = atomicExch(&head[s], e);
    rec[e] = make_int2(prev, d);   // coalesced 8B store — no write amplification
}

// ---------------- Kernel C: walk chain, out[i] = (g[i]+Σ g[dst]) / (es2[i]+Σ es2[dst])
// 32 lanes per node (lane = output col), 8 nodes per 256-thread block.
__global__ __launch_bounds__(256) void gat_aggregate(
    const float* __restrict__ g, const float* __restrict__ es2,
    const int* __restrict__ head, const int2* __restrict__ rec,
    float* __restrict__ out, int N)
{
    int tid = threadIdx.x;
    int i = blockIdx.x * 8 + (tid >> 5);
    if (i >= N) return;
    int col = tid & 31;

    float d = es2[i];                       // self-loop weight
    float acc = g[(long)i * DOUT + col];    // self-loop numerator

    int e = head[i];
    while (e >= 0) {
        int2 r = rec[e];                    // 8B broadcast load (critical chain)
        float ev = es2[r.y];                // off-chain broadcast gather
        acc += g[(long)r.y * DOUT + col];   // off-chain coalesced 128B row
        d += ev;
        e = r.x;
    }
    out[(long)i * DOUT + col] = acc / d;
}

extern "C" void kernel_launch(void* const* d_in, const int* in_sizes, int n_in,
                              void* d_out, int out_size, void* d_ws, size_t ws_size,
                              hipStream_t stream)
{
    const float* x  = (const float*)d_in[0];
    const int*   ei = (const int*)d_in[1];
    const float* W  = (const float*)d_in[2];
    const float* b  = (const float*)d_in[3];
    // d_in[4] = a1_w: unused — s1 cancels inside the segment softmax.
    const float* a2 = (const float*)d_in[5];
    float* out = (float*)d_out;

    int N = in_sizes[0] / DIN;
    int E = in_sizes[1] / 2;
    const int* src = ei;
    const int* dst = ei + E;

    char* ws = (char*)d_ws;
    float* g    = (float*)ws;  ws += (size_t)N * DOUT * sizeof(float);
    float* es2  = (float*)ws;  ws += (size_t)N * sizeof(float);
    int*   head = (int*)ws;    ws += (size_t)N * sizeof(int);
    int2*  rec  = (int2*)ws;   ws += (size_t)E * sizeof(int2);

    hipMemsetAsync(head, 0xFF, (size_t)N * sizeof(int), stream);  // head[i] = -1
    gat_linear   <<<(N + 7) / 8,     256, 0, stream>>>(x, W, b, a2, g, es2, N);
    gat_build    <<<(E + 255) / 256, 256, 0, stream>>>(src, dst, E, head, rec);
    gat_aggregate<<<(N + 7) / 8,     256, 0, stream>>>(g, es2, head, rec, out, N);
}

// Round 3
// 287.876 us; speedup vs baseline: 1.4471x; 1.0646x over previous
//
#include <hip/hip_runtime.h>
#include <hip/hip_fp16.h>

#define DIN 128
#define DOUT 32
#define SLOPE 0.2f

// ---------------- Kernel A: h = x@W^T + b ; es2 = exp(leaky(h)@a2) ; g16 = fp16(es2*h)
// Register-tiled 4x4: block = 256 threads covers 128 rows x 32 cols.
// cg = tid&7 -> cols cg*4..+3 ; rg = tid>>3 -> rows rg*4..+3.
// k-major LDS layouts so all compute reads are conflict-free ds_read_b128.
__global__ __launch_bounds__(256) void gat_linear(
    const float* __restrict__ x, const float* __restrict__ W,
    const float* __restrict__ b, const float* __restrict__ a2,
    __half* __restrict__ g16, float* __restrict__ es2, int N)
{
    __shared__ float Wt[DIN * DOUT];   // [k][col], stride 32: lanes read 4cg..4cg+3 -> conflict-free
    __shared__ float xs[32 * 132];     // [k in chunk][row], stride 132: banks 4k+4rg -> conflict-free
    int tid = threadIdx.x;
    int cg = tid & 7, rg = tid >> 3;
    int rowbase = blockIdx.x * 128;

    for (int idx = tid; idx < DOUT * DIN; idx += 256) {
        int col = idx >> 7, k = idx & 127;
        Wt[k * DOUT + col] = W[idx];   // one-time transpose; write conflicts negligible
    }

    float acc[4][4] = {};
    for (int kc = 0; kc < 4; ++kc) {
        __syncthreads();               // xs reuse guard (also orders Wt writes on kc==0)
        #pragma unroll
        for (int it = 0; it < 4; ++it) {
            int sid = it * 256 + tid;          // 0..1023 float4s = 128 rows x 32 k
            int r = sid >> 3;
            int kk = (sid & 7) * 4;
            int row = rowbase + r;
            float4 v = make_float4(0.f, 0.f, 0.f, 0.f);
            if (row < N) v = *(const float4*)&x[(long)row * DIN + kc * 32 + kk];
            xs[(kk + 0) * 132 + r] = v.x;
            xs[(kk + 1) * 132 + r] = v.y;
            xs[(kk + 2) * 132 + r] = v.z;
            xs[(kk + 3) * 132 + r] = v.w;
        }
        __syncthreads();
        #pragma unroll
        for (int k = 0; k < 32; ++k) {
            float4 xr = *(const float4*)&xs[k * 132 + rg * 4];
            float4 wv = *(const float4*)&Wt[(kc * 32 + k) * DOUT + cg * 4];
            acc[0][0] += xr.x * wv.x; acc[0][1] += xr.x * wv.y;
            acc[0][2] += xr.x * wv.z; acc[0][3] += xr.x * wv.w;
            acc[1][0] += xr.y * wv.x; acc[1][1] += xr.y * wv.y;
            acc[1][2] += xr.y * wv.z; acc[1][3] += xr.y * wv.w;
            acc[2][0] += xr.z * wv.x; acc[2][1] += xr.z * wv.y;
            acc[2][2] += xr.z * wv.z; acc[2][3] += xr.z * wv.w;
            acc[3][0] += xr.w * wv.x; acc[3][1] += xr.w * wv.y;
            acc[3][2] += xr.w * wv.z; acc[3][3] += xr.w * wv.w;
        }
    }

    int colb = cg * 4;
    float bv0 = b[colb], bv1 = b[colb + 1], bv2 = b[colb + 2], bv3 = b[colb + 3];
    float av0 = a2[colb], av1 = a2[colb + 1], av2 = a2[colb + 2], av3 = a2[colb + 3];
    #pragma unroll
    for (int i = 0; i < 4; ++i) {
        int r = rowbase + rg * 4 + i;
        if (r >= N) continue;          // uniform across the 8-lane shuffle group -> safe
        float h0 = acc[i][0] + bv0, h1 = acc[i][1] + bv1;
        float h2 = acc[i][2] + bv2, h3 = acc[i][3] + bv3;
        float p = (h0 > 0.f ? h0 : SLOPE * h0) * av0
                + (h1 > 0.f ? h1 : SLOPE * h1) * av1
                + (h2 > 0.f ? h2 : SLOPE * h2) * av2
                + (h3 > 0.f ? h3 : SLOPE * h3) * av3;
        p += __shfl_xor(p, 1, 8);
        p += __shfl_xor(p, 2, 8);
        p += __shfl_xor(p, 4, 8);      // all 8 lanes of the row now hold s2[r]
        float ev = __expf(p);          // softmax shift-invariance: no segment max needed
        union { __half h[4]; short4 s; } u;
        u.h[0] = __float2half(ev * h0); u.h[1] = __float2half(ev * h1);
        u.h[2] = __float2half(ev * h2); u.h[3] = __float2half(ev * h3);
        *(short4*)&g16[(long)r * DOUT + colb] = u.s;   // 8B store, coalesced
        if (cg == 0) es2[r] = ev;
    }
}

// ---------------- Kernel B: build per-src linked lists (coalesced writes) ---
__global__ __launch_bounds__(256) void gat_build(
    const int* __restrict__ src, const int* __restrict__ dst, int E,
    int* __restrict__ head, int2* __restrict__ rec)
{
    int e = blockIdx.x * 256 + threadIdx.x;
    if (e >= E) return;
    int s = src[e];
    int d = dst[e];
    int prev = atomicExch(&head[s], e);
    rec[e] = make_int2(prev, d);   // coalesced 8B store
}

// ---------------- Kernel C: walk chain; out[i] = (g[i]+Σ g[dst]) / (es2[i]+Σ es2[dst])
__global__ __launch_bounds__(256) void gat_aggregate(
    const __half* __restrict__ g16, const float* __restrict__ es2,
    const int* __restrict__ head, const int2* __restrict__ rec,
    float* __restrict__ out, int N)
{
    int tid = threadIdx.x;
    int i = blockIdx.x * 8 + (tid >> 5);
    if (i >= N) return;
    int col = tid & 31;

    float d = es2[i];
    float acc = __half2float(g16[(long)i * DOUT + col]);

    int e = head[i];
    while (e >= 0) {
        int2 r = rec[e];                               // 8B broadcast (critical chain)
        d += es2[r.y];                                 // L2-resident 0.4MB
        acc += __half2float(g16[(long)r.y * DOUT + col]);  // 64B row gather
        e = r.x;
    }
    out[(long)i * DOUT + col] = acc / d;
}

extern "C" void kernel_launch(void* const* d_in, const int* in_sizes, int n_in,
                              void* d_out, int out_size, void* d_ws, size_t ws_size,
                              hipStream_t stream)
{
    const float* x  = (const float*)d_in[0];
    const int*   ei = (const int*)d_in[1];
    const float* W  = (const float*)d_in[2];
    const float* b  = (const float*)d_in[3];
    // d_in[4] = a1_w: unused — s1 cancels inside the segment softmax.
    const float* a2 = (const float*)d_in[5];
    float* out = (float*)d_out;

    int N = in_sizes[0] / DIN;
    int E = in_sizes[1] / 2;
    const int* src = ei;
    const int* dst = ei + E;

    char* ws = (char*)d_ws;
    __half* g16 = (__half*)ws; ws += (size_t)N * DOUT * sizeof(__half);
    float* es2  = (float*)ws;  ws += (size_t)N * sizeof(float);
    int*   head = (int*)ws;    ws += (size_t)N * sizeof(int);
    // align rec to 8B
    ws = (char*)(((uintptr_t)ws + 7) & ~(uintptr_t)7);
    int2*  rec  = (int2*)ws;   ws += (size_t)E * sizeof(int2);

    hipMemsetAsync(head, 0xFF, (size_t)N * sizeof(int), stream);  // head[i] = -1
    gat_linear   <<<(N + 127) / 128, 256, 0, stream>>>(x, W, b, a2, g16, es2, N);
    gat_build    <<<(E + 255) / 256, 256, 0, stream>>>(src, dst, E, head, rec);
    gat_aggregate<<<(N + 7) / 8,     256, 0, stream>>>(g16, es2, head, rec, out, N);
}

// Round 4
// 280.586 us; speedup vs baseline: 1.4847x; 1.0260x over previous
//
#include <hip/hip_runtime.h>
#include <hip/hip_fp16.h>

#define DIN 128
#define DOUT 32
#define SLOPE 0.2f

typedef short s16x8 __attribute__((ext_vector_type(8)));   // 8 bf16 (4 VGPRs)
typedef float f32x4 __attribute__((ext_vector_type(4)));   // MFMA C/D frag

__device__ __forceinline__ short f2bf(float f) {          // fp32 -> bf16 (RNE)
    unsigned u = __float_as_uint(f);
    return (short)((u + 0x7fffu + ((u >> 16) & 1u)) >> 16);
}
__device__ __forceinline__ float bf2f(short s) {
    return __uint_as_float(((unsigned)(unsigned short)s) << 16);
}

// ---------------- Linear role: one wave computes 16 rows of h via MFMA -------
// A = x-tile (16x32 per kc), B[k][n] = W[n][k]. hi/lo bf16 split both sides,
// 3 MFMAs per (n-tile, kc) => fp32-level accuracy (~1e-4 on h).
// A-frag: lane holds A[m=lane&15][k=(lane>>4)*8+j]; B-frag: B[k=(lane>>4)*8+j][n=lane&15].
// C/D: col=lane&15, row=(lane>>4)*4+reg.
__device__ __forceinline__ void linear_role(
    int tile, int ntiles, int lane, int N,
    const float* __restrict__ x, const float* __restrict__ W,
    const float* __restrict__ b, const float* __restrict__ a2,
    __half* __restrict__ g16, float* __restrict__ es2)
{
    if (tile >= ntiles) return;
    int m = lane & 15, oct = lane >> 4;
    long rowbase = (long)tile * 16;

    // Preload B frags (hi/lo) for 2 n-tiles x 4 k-chunks (W is 16KB, L2-hot)
    s16x8 bh[2][4], bl[2][4];
    #pragma unroll
    for (int t = 0; t < 2; ++t) {
        const float* wrow = W + (long)(t * 16 + m) * DIN + oct * 8;
        #pragma unroll
        for (int kc = 0; kc < 4; ++kc) {
            float4 w0 = *(const float4*)(wrow + kc * 32);
            float4 w1 = *(const float4*)(wrow + kc * 32 + 4);
            float wf[8] = {w0.x, w0.y, w0.z, w0.w, w1.x, w1.y, w1.z, w1.w};
            #pragma unroll
            for (int j = 0; j < 8; ++j) {
                short hh = f2bf(wf[j]);
                bh[t][kc][j] = hh;
                bl[t][kc][j] = f2bf(wf[j] - bf2f(hh));
            }
        }
    }

    long lrow = rowbase + m; if (lrow > N - 1) lrow = N - 1;   // load clamp
    const float* xrow = x + lrow * DIN + oct * 8;
    f32x4 acc0 = {0.f, 0.f, 0.f, 0.f}, acc1 = {0.f, 0.f, 0.f, 0.f};
    #pragma unroll
    for (int kc = 0; kc < 4; ++kc) {
        float4 x0 = *(const float4*)(xrow + kc * 32);
        float4 x1 = *(const float4*)(xrow + kc * 32 + 4);
        float xf[8] = {x0.x, x0.y, x0.z, x0.w, x1.x, x1.y, x1.z, x1.w};
        s16x8 ah, al;
        #pragma unroll
        for (int j = 0; j < 8; ++j) {
            short hh = f2bf(xf[j]);
            ah[j] = hh;
            al[j] = f2bf(xf[j] - bf2f(hh));
        }
        acc0 = __builtin_amdgcn_mfma_f32_16x16x32_bf16(al, bh[0][kc], acc0, 0, 0, 0);
        acc0 = __builtin_amdgcn_mfma_f32_16x16x32_bf16(ah, bl[0][kc], acc0, 0, 0, 0);
        acc0 = __builtin_amdgcn_mfma_f32_16x16x32_bf16(ah, bh[0][kc], acc0, 0, 0, 0);
        acc1 = __builtin_amdgcn_mfma_f32_16x16x32_bf16(al, bh[1][kc], acc1, 0, 0, 0);
        acc1 = __builtin_amdgcn_mfma_f32_16x16x32_bf16(ah, bl[1][kc], acc1, 0, 0, 0);
        acc1 = __builtin_amdgcn_mfma_f32_16x16x32_bf16(ah, bh[1][kc], acc1, 0, 0, 0);
    }

    // Epilogue: bias, leaky, s2 = sum_c z*a2 (reduce over 16 lanes), exp, store
    int c0 = m, c1 = 16 + m;
    float b0 = b[c0], b1 = b[c1], A0 = a2[c0], A1 = a2[c1];
    float hv0[4], hv1[4], sp[4];
    #pragma unroll
    for (int i = 0; i < 4; ++i) {
        hv0[i] = acc0[i] + b0;
        hv1[i] = acc1[i] + b1;
        float z0 = hv0[i] > 0.f ? hv0[i] : SLOPE * hv0[i];
        float z1 = hv1[i] > 0.f ? hv1[i] : SLOPE * hv1[i];
        sp[i] = z0 * A0 + z1 * A1;
    }
    #pragma unroll
    for (int off = 1; off <= 8; off <<= 1) {   // reduce across m (stays in oct group)
        #pragma unroll
        for (int i = 0; i < 4; ++i) sp[i] += __shfl_xor(sp[i], off, 64);
    }
    #pragma unroll
    for (int i = 0; i < 4; ++i) {
        long r = rowbase + oct * 4 + i;
        if (r >= N) continue;
        float ev = __expf(sp[i]);              // shift-invariant softmax: no max pass
        g16[r * DOUT + c0] = __float2half(ev * hv0[i]);
        g16[r * DOUT + c1] = __float2half(ev * hv1[i]);
        if (m == 0) es2[r] = ev;
    }
}

// ---------------- Fused kernel: linear blocks + build blocks -----------------
__global__ __launch_bounds__(256) void gat_fused(
    const float* __restrict__ x, const float* __restrict__ W,
    const float* __restrict__ b, const float* __restrict__ a2,
    const int* __restrict__ src, const int* __restrict__ dst,
    __half* __restrict__ g16, float* __restrict__ es2,
    int* __restrict__ head4, int2* __restrict__ rec,
    int N, int E, int ntiles, int nlin)
{
    if ((int)blockIdx.x < nlin) {
        int wave = threadIdx.x >> 6;
        int tile = blockIdx.x * 4 + wave;
        linear_role(tile, ntiles, threadIdx.x & 63, N, x, W, b, a2, g16, es2);
    } else {
        int e = (blockIdx.x - nlin) * 256 + threadIdx.x;
        if (e < E) {
            int s = src[e];
            int d = dst[e];
            int prev = atomicExch(&head4[s * 4 + (e & 3)], e);
            rec[e] = make_int2(prev, d);       // coalesced 8B store
        }
    }
}

// ---------------- Aggregate: walk 4 chains/node (4-deep MLP on the chase) ----
__global__ __launch_bounds__(256) void gat_aggregate(
    const __half* __restrict__ g16, const float* __restrict__ es2,
    const int* __restrict__ head4, const int2* __restrict__ rec,
    float* __restrict__ out, int N)
{
    int tid = threadIdx.x;
    int i = blockIdx.x * 8 + (tid >> 5);
    if (i >= N) return;
    int col = tid & 31;

    float d = es2[i];                                  // self-loop
    float acc = __half2float(g16[(long)i * DOUT + col]);

    int e0 = head4[i * 4 + 0], e1 = head4[i * 4 + 1];
    int e2 = head4[i * 4 + 2], e3 = head4[i * 4 + 3];
    while ((e0 >= 0) | (e1 >= 0) | (e2 >= 0) | (e3 >= 0)) {
        int2 r0, r1, r2, r3;
        bool a0 = e0 >= 0, a1 = e1 >= 0, a2v = e2 >= 0, a3 = e3 >= 0;
        if (a0) r0 = rec[e0];                          // 4 independent chase loads
        if (a1) r1 = rec[e1];
        if (a2v) r2 = rec[e2];
        if (a3) r3 = rec[e3];
        if (a0) { d += es2[r0.y]; acc += __half2float(g16[(long)r0.y * DOUT + col]); e0 = r0.x; }
        if (a1) { d += es2[r1.y]; acc += __half2float(g16[(long)r1.y * DOUT + col]); e1 = r1.x; }
        if (a2v){ d += es2[r2.y]; acc += __half2float(g16[(long)r2.y * DOUT + col]); e2 = r2.x; }
        if (a3) { d += es2[r3.y]; acc += __half2float(g16[(long)r3.y * DOUT + col]); e3 = r3.x; }
    }
    out[(long)i * DOUT + col] = acc / d;
}

extern "C" void kernel_launch(void* const* d_in, const int* in_sizes, int n_in,
                              void* d_out, int out_size, void* d_ws, size_t ws_size,
                              hipStream_t stream)
{
    const float* x  = (const float*)d_in[0];
    const int*   ei = (const int*)d_in[1];
    const float* W  = (const float*)d_in[2];
    const float* b  = (const float*)d_in[3];
    // d_in[4] = a1_w: unused — s1 cancels inside the segment softmax.
    const float* a2 = (const float*)d_in[5];
    float* out = (float*)d_out;

    int N = in_sizes[0] / DIN;
    int E = in_sizes[1] / 2;
    const int* src = ei;
    const int* dst = ei + E;

    char* ws = (char*)d_ws;
    __half* g16  = (__half*)ws; ws += (size_t)N * DOUT * sizeof(__half);
    float*  es2  = (float*)ws;  ws += (size_t)N * sizeof(float);
    int*    head4= (int*)ws;    ws += (size_t)N * 4 * sizeof(int);
    ws = (char*)(((uintptr_t)ws + 7) & ~(uintptr_t)7);
    int2*   rec  = (int2*)ws;   ws += (size_t)E * sizeof(int2);

    int ntiles = (N + 15) / 16;          // 6250
    int nlin   = (ntiles + 3) / 4;       // 1563 linear blocks (4 waves/block)
    int nbuild = (E + 255) / 256;        // 6250 build blocks

    hipMemsetAsync(head4, 0xFF, (size_t)N * 4 * sizeof(int), stream);  // -1
    gat_fused    <<<nlin + nbuild, 256, 0, stream>>>(x, W, b, a2, src, dst,
                                                     g16, es2, head4, rec,
                                                     N, E, ntiles, nlin);
    gat_aggregate<<<(N + 7) / 8, 256, 0, stream>>>(g16, es2, head4, rec, out, N);
}